// Round 5
// baseline (10893.026 us; speedup 1.0000x reference)
//
#include <hip/hip_runtime.h>
#include <math.h>

#define T_STEPS 1024
#define BATCH   512
#define DZ      256
#define DH      256
#define RANK    8
#define DY      16

// 512 blocks x 1024 threads, 1 batch element per block -> 2 blocks/CU
// (32 waves/CU): one block's compute hides the other's barrier stalls.
// 3 barriers/step (was 5):
//   A -> {W_zz+W_in dot2 partials, out(t-1), tanh(h)@V in-register} ->
//   B -> {z-update (waves 0-3) || rz/signal/gl (waves 8-15)} ->
//   C -> {h-update + input publish} -> A
// signal projection rz = z @ Wz_out[r] is maintained INCREMENTALLY
// (rz_t = .99 rz_{t-1} + .01 tmp@wzo[r], from the same redz partials),
// removing the z-publish -> signal -> h serial barriers.
// Weights are f16-packed in VGPRs (44 regs) consumed by v_dot2_f32_f16
// (f32 accumulate) so the persistent live set fits the 64-VGPR budget
// that 8 waves/EU implies (R1-R3 lesson: f32 weights spill).

typedef _Float16 h2 __attribute__((ext_vector_type(2)));

__device__ __forceinline__ h2 pack2(float a, float b) {
    h2 r; r.x = (_Float16)a; r.y = (_Float16)b; return r;
}
__device__ __forceinline__ h2 bc(unsigned u) { return __builtin_bit_cast(h2, u); }

__device__ __forceinline__ float dot2(h2 a, h2 b, float c) {
#if __has_builtin(__builtin_amdgcn_fdot2)
    return __builtin_amdgcn_fdot2(a, b, c, false);
#else
    return fmaf((float)a.x, (float)b.x, fmaf((float)a.y, (float)b.y, c));
#endif
}

__device__ __forceinline__ float fast_tanh(float x) {
    const float e = __expf(2.0f * x);          // v_exp_f32 path
    return 1.0f - 2.0f / (e + 1.0f);
}

__global__ __launch_bounds__(1024, 8)
void nmrnn_kernel(
    const float* __restrict__ s, const float* __restrict__ c,
    const float* __restrict__ W_zz, const float* __restrict__ Wz_in,
    const float* __restrict__ bz_in, const float* __restrict__ Wz_out,
    const float* __restrict__ bz_out, const float* __restrict__ U,
    const float* __restrict__ V, const float* __restrict__ W_in,
    const float* __restrict__ b_in, const float* __restrict__ W_out,
    const float* __restrict__ b_out,
    float* __restrict__ out, float* __restrict__ states)
{
    __shared__ __align__(16) _Float16 tzh[DZ];   // tanh(z) f16
    __shared__ __align__(16) _Float16 sclh[64];  // [s_t|c_t] f16
    __shared__ __align__(16) float th[DH];       // tanh(h) f32
    __shared__ __align__(16) float redz[4][DZ];  // z-dot partials
    __shared__ __align__(16) float redh[4][DH];  // W_in-dot partials
    __shared__ __align__(16) float wzo[RANK][DZ];// Wz_out [r][k]
    __shared__ __align__(16) float vt[RANK][DH]; // V^T  [r][k]
    __shared__ __align__(16) float ut[RANK][DH]; // U^T  [r][i]
    __shared__ __align__(16) float wo[DY][DH];   // W_out [y][k]
    __shared__ float gl[RANK];                   // signal * (tanh(h)@V)
    __shared__ float bo[DY];

    const int tid = threadIdx.x;
    const int i   = tid & 255;
    const int q   = tid >> 8;          // 0..3  k-quadrant
    const int g   = tid >> 6;          // 0..15 64-lane group
    const int l   = tid & 63;
    const int b   = blockIdx.x;        // one batch element

    // ---- register-resident f16-packed weights ----
    h2 wzzp[32];
    #pragma unroll
    for (int m = 0; m < 16; ++m) {
        const float4 v4 = *reinterpret_cast<const float4*>(&W_zz[i * 256 + (q << 6) + (m << 2)]);
        wzzp[2 * m]     = pack2(v4.x, v4.y);
        wzzp[2 * m + 1] = pack2(v4.z, v4.w);
    }
    h2 wzip[8];
    #pragma unroll
    for (int m = 0; m < 4; ++m) {
        const float4 v4 = *reinterpret_cast<const float4*>(&Wz_in[i * 64 + (q << 4) + (m << 2)]);
        wzip[2 * m]     = pack2(v4.x, v4.y);
        wzip[2 * m + 1] = pack2(v4.z, v4.w);
    }
    h2 wip[4];
    #pragma unroll
    for (int m = 0; m < 2; ++m) {
        const float4 v4 = *reinterpret_cast<const float4*>(&W_in[i * 32 + (q << 3) + (m << 2)]);
        wip[2 * m]     = pack2(v4.x, v4.y);
        wip[2 * m + 1] = pack2(v4.z, v4.w);
    }

    // ---- stage small f32 matrices in LDS ----
    if (tid < 512) {  // Wz_out: 2048 floats
        const float4 v4 = *reinterpret_cast<const float4*>(&Wz_out[tid * 4]);
        *reinterpret_cast<float4*>(&((float*)wzo)[tid * 4]) = v4;
    }
    {   // W_out: 4096 floats
        const float4 v4 = *reinterpret_cast<const float4*>(&W_out[tid * 4]);
        *reinterpret_cast<float4*>(&((float*)wo)[tid * 4]) = v4;
    }
    if (tid < 256) {  // transpose V, U
        #pragma unroll
        for (int r = 0; r < RANK; ++r) vt[r][tid] = V[tid * RANK + r];
        #pragma unroll
        for (int r = 0; r < RANK; ++r) ut[r][tid] = U[tid * RANK + r];
    }
    if (tid < DY) bo[tid] = b_out[tid];

    const float bzi_r = (tid < 256) ? bz_in[i] : 0.f;
    const float bi_r  = (tid < 256) ? b_in[i]  : 0.f;
    float z_r = 0.f, h_r = 0.f;

    if (tid < 256) { tzh[i] = (_Float16)0.f; th[i] = 0.f; }
    __syncthreads();   // wzo staged

    // ---- zp-wave persistent registers (waves 8-15, r = g&7) ----
    // czb = bz_in @ wzo[r] + bzo[r]   (folded constant)
    // rzb = z @ wzo[r] + bzo[r]       (incremental; init = bzo[r] since z0=0)
    float czb_r = 0.f, rzb_r = 0.f;
    if (g >= 8) {
        const int r = g & 7;
        float cz = 0.f;
        #pragma unroll
        for (int m = 0; m < 4; ++m) {
            const int k = l + 64 * m;
            cz = fmaf(bz_in[k], wzo[r][k], cz);
        }
        #pragma unroll
        for (int off = 32; off >= 1; off >>= 1) cz += __shfl_xor(cz, off);
        const float bzo_r = bz_out[r];
        czb_r = cz + bzo_r;
        rzb_r = bzo_r;
    }

    // publish t=0 inputs
    if (tid < 64) {
        const size_t base = (size_t)b * 32;
        sclh[tid] = (_Float16)((l < 32) ? s[base + l] : c[base + l - 32]);
    }
    float pfn = 0.f;
    __syncthreads();   // A0

    for (int t = 0; t < T_STEPS; ++t) {
        // ================= A..B =================
        // prefetch next step's input (consumed at C..A')
        if (tid < 64 && t + 1 < T_STEPS) {
            const size_t base = ((size_t)(t + 1) * BATCH + b) * 32;
            pfn = (l < 32) ? s[base + l] : c[base + l - 32];
        }

        // hp = tanh(h_{t-1}) @ V[:,r]  (waves 8-15, kept in-register)
        float hp_r = 0.f;
        if (g >= 8) {
            const int r = g & 7;
            #pragma unroll
            for (int m = 0; m < 4; ++m) {
                const int k = l + 64 * m;
                hp_r = fmaf(th[k], vt[r][k], hp_r);
            }
            #pragma unroll
            for (int off = 32; off >= 1; off >>= 1) hp_r += __shfl_xor(hp_r, off);
        }

        // out(t-1): th still holds tanh(h_{t-1})
        if (t > 0) {
            float o = 0.f;
            #pragma unroll
            for (int m = 0; m < 4; ++m) {
                const int k = l + 64 * m;
                o = fmaf(th[k], wo[g][k], o);
            }
            #pragma unroll
            for (int off = 32; off >= 1; off >>= 1) o += __shfl_xor(o, off);
            if (l == 0) out[((size_t)(t - 1) * BATCH + b) * 16 + g] = o + bo[g];
        }

        // z partial dots (W_zz quadrant + Wz_in) and W_in partial dots
        {
            float az = 0.f, ah = 0.f;
            const uint4* t0p = reinterpret_cast<const uint4*>(&tzh[q << 6]);
            #pragma unroll
            for (int m = 0; m < 8; ++m) {
                const uint4 u0 = t0p[m];
                az = dot2(wzzp[4 * m + 0], bc(u0.x), az);
                az = dot2(wzzp[4 * m + 1], bc(u0.y), az);
                az = dot2(wzzp[4 * m + 2], bc(u0.z), az);
                az = dot2(wzzp[4 * m + 3], bc(u0.w), az);
            }
            const uint4* s0p = reinterpret_cast<const uint4*>(&sclh[q << 4]);
            #pragma unroll
            for (int m = 0; m < 2; ++m) {
                const uint4 u0 = s0p[m];
                az = dot2(wzip[4 * m + 0], bc(u0.x), az);
                az = dot2(wzip[4 * m + 1], bc(u0.y), az);
                az = dot2(wzip[4 * m + 2], bc(u0.z), az);
                az = dot2(wzip[4 * m + 3], bc(u0.w), az);
            }
            const uint4 u0 = *reinterpret_cast<const uint4*>(&sclh[q << 3]);
            ah = dot2(wip[0], bc(u0.x), ah);
            ah = dot2(wip[1], bc(u0.y), ah);
            ah = dot2(wip[2], bc(u0.z), ah);
            ah = dot2(wip[3], bc(u0.w), ah);
            redz[q][i] = az;
            redh[q][i] = ah;
        }
        __syncthreads();  // B

        // ================= B..C =================
        if (tid < 256) {
            // z update
            const float tmp = redz[0][i] + redz[1][i] + redz[2][i] + redz[3][i] + bzi_r;
            z_r = 0.99f * z_r + 0.01f * tmp;
            tzh[i] = (_Float16)fast_tanh(z_r);
            states[((size_t)t * BATCH + b) * 512 + i] = z_r;
        } else if (g >= 8) {
            // rz/signal/gl for rank r
            const int r = g & 7;
            float zp = 0.f;
            #pragma unroll
            for (int m = 0; m < 4; ++m) {
                const int k = l + 64 * m;
                const float rs = redz[0][k] + redz[1][k] + redz[2][k] + redz[3][k];
                zp = fmaf(rs, wzo[r][k], zp);
            }
            #pragma unroll
            for (int off = 32; off >= 1; off >>= 1) zp += __shfl_xor(zp, off);
            rzb_r = 0.99f * rzb_r + 0.01f * (zp + czb_r);
            const float sg = 1.f / (1.f + __expf(-rzb_r));
            if (l == 0) gl[r] = sg * hp_r;
        }
        __syncthreads();  // C

        // ================= C..A' =================
        if (tid < 256) {
            // h update: W_in partials + U @ (signal * tanh(h)@V)
            float tmp = redh[0][i] + redh[1][i] + redh[2][i] + redh[3][i] + bi_r;
            #pragma unroll
            for (int r = 0; r < RANK; ++r) tmp = fmaf(ut[r][i], gl[r], tmp);
            h_r = 0.9f * h_r + 0.1f * tmp;
            th[i] = fast_tanh(h_r);
            states[((size_t)t * BATCH + b) * 512 + 256 + i] = h_r;
        }
        if (tid < 64 && t + 1 < T_STEPS) sclh[tid] = (_Float16)pfn;
        __syncthreads();  // A
    }

    // ---- final out (t = T_STEPS-1): th = tanh(h_{T-1}) ----
    {
        float o = 0.f;
        #pragma unroll
        for (int m = 0; m < 4; ++m) {
            const int k = l + 64 * m;
            o = fmaf(th[k], wo[g][k], o);
        }
        #pragma unroll
        for (int off = 32; off >= 1; off >>= 1) o += __shfl_xor(o, off);
        if (l == 0) out[((size_t)(T_STEPS - 1) * BATCH + b) * 16 + g] = o + bo[g];
    }
}

extern "C" void kernel_launch(void* const* d_in, const int* in_sizes, int n_in,
                              void* d_out, int out_size, void* d_ws, size_t ws_size,
                              hipStream_t stream) {
    const float* s     = (const float*)d_in[0];
    const float* c     = (const float*)d_in[1];
    const float* W_zz  = (const float*)d_in[2];
    const float* Wz_in = (const float*)d_in[3];
    const float* bz_in = (const float*)d_in[4];
    const float* Wz_out= (const float*)d_in[5];
    const float* bz_out= (const float*)d_in[6];
    const float* U     = (const float*)d_in[7];
    const float* V     = (const float*)d_in[8];
    const float* W_in  = (const float*)d_in[9];
    const float* b_in  = (const float*)d_in[10];
    const float* W_out = (const float*)d_in[11];
    const float* b_out = (const float*)d_in[12];

    float* out    = (float*)d_out;
    float* states = out + (size_t)T_STEPS * BATCH * DY;

    hipLaunchKernelGGL(nmrnn_kernel, dim3(BATCH), dim3(1024), 0, stream,
                       s, c, W_zz, Wz_in, bz_in, Wz_out, bz_out, U, V,
                       W_in, b_in, W_out, b_out, out, states);
}

// Round 6
// 3044.741 us; speedup vs baseline: 3.5777x; 3.5777x over previous
//
#include <hip/hip_runtime.h>
#include <math.h>

#define T_STEPS 1024
#define BATCH   512

// MFMA rewrite. 32 blocks x 512 threads (8 waves), 16 batch rows/block for
// all T steps. Wave w owns output cols [32w, 32w+32) of both z and h.
// W_zz lives as f16 MFMA B-fragments in VGPRs (64 regs); z/h accumulators
// persist in VGPRs in C/D layout; all A-panels (tanh z, z, [s|c], gm,
// tanh h) are f16 in LDS with XOR swizzle (row-stride panels are 16-way
// bank conflicts unswizzled). 512-thread blocks escape the 64-VGPR cap
// that 1024-thread blocks provoked in R1-R5 (observed 64/64/64/64/32).
//
// mfma_f32_16x16x32_f16 layouts (CDNA4):
//   A[m][k]: lane = m + 16*(k/8), elem j = k%8
//   B[k][n]: lane = n + 16*(k/8), elem j = k%8
//   C/D:     col = lane&15, row = (lane>>4)*4 + reg      (m89-verified)
// Update folding: C_in = 99*z + bz; z_new = 0.01 * D  (0.99/0.01 = 99).

typedef _Float16 f16;
typedef _Float16 v8h __attribute__((ext_vector_type(8)));
typedef float v4f __attribute__((ext_vector_type(4)));

__device__ __forceinline__ float fast_tanh(float x) {
    const float e = __expf(2.0f * x);
    return 1.0f - 2.0f / (e + 1.0f);
}

__device__ __forceinline__ v8h pack8(float4 a, float4 b) {
    v8h r;
    r[0]=(f16)a.x; r[1]=(f16)a.y; r[2]=(f16)a.z; r[3]=(f16)a.w;
    r[4]=(f16)b.x; r[5]=(f16)b.y; r[6]=(f16)b.z; r[7]=(f16)b.w;
    return r;
}

// swizzled A-panel access: byte = m*STRIDE + k*2, XOR ((m&MASK)<<4)
template<int STRIDE>
__device__ __forceinline__ v8h lda(const f16* base, int m, int lg, int kt) {
    constexpr int MASK = (STRIDE >= 128) ? 7 : 3;
    int byte = m * STRIDE + kt * 64 + lg * 16;
    byte ^= (m & MASK) << 4;
    return *reinterpret_cast<const v8h*>(reinterpret_cast<const char*>(base) + byte);
}
template<int STRIDE>
__device__ __forceinline__ void sta(f16* base, int m, int k, f16 v) {
    constexpr int MASK = (STRIDE >= 128) ? 7 : 3;
    int byte = m * STRIDE + k * 2;
    byte ^= (m & MASK) << 4;
    *reinterpret_cast<f16*>(reinterpret_cast<char*>(base) + byte) = v;
}

__global__ __launch_bounds__(512, 2) void nmrnn_mfma(
    const float* __restrict__ s, const float* __restrict__ c,
    const float* __restrict__ W_zz, const float* __restrict__ Wz_in,
    const float* __restrict__ bz_in, const float* __restrict__ Wz_out,
    const float* __restrict__ bz_out, const float* __restrict__ U,
    const float* __restrict__ V, const float* __restrict__ W_in,
    const float* __restrict__ b_in, const float* __restrict__ W_out,
    const float* __restrict__ b_out,
    float* __restrict__ out, float* __restrict__ states)
{
    // A-panels (f16, swizzled)
    __shared__ __align__(16) f16 tzh[2][16 * 256];   // tanh(z), dbuf
    __shared__ __align__(16) f16 thh[2][16 * 256];   // tanh(h), dbuf
    __shared__ __align__(16) f16 zfl[16 * 256];      // z_t (for sig)
    __shared__ __align__(16) f16 sclh[2][16 * 64];   // [s|c], dbuf
    __shared__ __align__(16) f16 gml[16 * 32];       // sig*hp, K-pad 32
    // B-fragments staged in LDS (frag-linear: [tile][lane*8+j])
    __shared__ __align__(16) f16 wzin_f[32][512];    // [nt*2+kt]
    __shared__ __align__(16) f16 win_f[16][512];     // [nt]
    __shared__ __align__(16) f16 wzout_f[8][512];    // [kt], cols 8-15 zero
    __shared__ __align__(16) f16 vv_f[8][512];       // [kt], cols 8-15 zero
    __shared__ __align__(16) f16 wout_f[8][512];     // [kt]
    // cross-wave reduction scratch
    __shared__ float pout[8][16][16];
    __shared__ float php[8][16][8];
    __shared__ float psig[8][16][8];
    __shared__ float hpv[16][8];
    __shared__ float bzo8[8];
    __shared__ float bo16[16];

    const int tid = threadIdx.x;
    const int w  = tid >> 6;        // wave 0..7
    const int l  = tid & 63;
    const int lr = l & 15;
    const int lg = l >> 4;
    const int bm = blockIdx.x * 16; // batch row base
    const int n0 = w * 32 + lr;     // col, ct=0
    const int n1 = n0 + 16;         // col, ct=1

    // ---- persistent register B-fragments: W_zz (64 VGPR), U (8) ----
    v8h wzz0[8], wzz1[8];
    #pragma unroll
    for (int kt = 0; kt < 8; ++kt) {
        const int kb = kt * 32 + lg * 8;
        const float4 a0 = *(const float4*)&W_zz[n0 * 256 + kb];
        const float4 b0 = *(const float4*)&W_zz[n0 * 256 + kb + 4];
        wzz0[kt] = pack8(a0, b0);
        const float4 a1 = *(const float4*)&W_zz[n1 * 256 + kb];
        const float4 b1 = *(const float4*)&W_zz[n1 * 256 + kb + 4];
        wzz1[kt] = pack8(a1, b1);
    }
    v8h u0 = {}, u1 = {};
    if (lg == 0) {  // B[k][n] = U[n][k], k<8; k>=8 zero-padded
        const float4 a0 = *(const float4*)&U[n0 * 8];
        const float4 b0 = *(const float4*)&U[n0 * 8 + 4];
        u0 = pack8(a0, b0);
        const float4 a1 = *(const float4*)&U[n1 * 8];
        const float4 b1 = *(const float4*)&U[n1 * 8 + 4];
        u1 = pack8(a1, b1);
    }
    const float bzv0 = bz_in[n0], bzv1 = bz_in[n1];
    const float biv0 = b_in[n0],  biv1 = b_in[n1];

    // ---- zero tanh panels (z0=h0=0) and gm pad ----
    {
        uint32_t* p0 = (uint32_t*)tzh[0];
        uint32_t* p1 = (uint32_t*)thh[0];
        #pragma unroll
        for (int it = 0; it < 4; ++it) { p0[tid + 512 * it] = 0; p1[tid + 512 * it] = 0; }
        if (tid < 256) ((uint32_t*)gml)[tid] = 0;
    }
    // ---- stage t=0 inputs ----
    {
        const int row = tid >> 5, col = tid & 31;
        const float sv = s[(size_t)(bm + row) * 32 + col];
        const float cv = c[(size_t)(bm + row) * 32 + col];
        sta<128>(sclh[0], row, col, (f16)sv);
        sta<128>(sclh[0], row, 32 + col, (f16)cv);
    }
    // ---- stage B-fragments in LDS ----
    #pragma unroll
    for (int it = 0; it < 4; ++it) {  // Wz_in: B[k][n]=Wz_in[n][k], 32 tiles
        const int e = tid + 512 * it;
        const int tile = e >> 6, ln = e & 63;
        const int nt = tile >> 1, kt = tile & 1;
        const int row = nt * 16 + (ln & 15);
        const int kb  = kt * 32 + (ln >> 4) * 8;
        const float4 a = *(const float4*)&Wz_in[row * 64 + kb];
        const float4 b = *(const float4*)&Wz_in[row * 64 + kb + 4];
        *(v8h*)&wzin_f[tile][ln * 8] = pack8(a, b);
    }
    #pragma unroll
    for (int it = 0; it < 2; ++it) {  // W_in: B[k][n]=W_in[n][k], 16 tiles
        const int e = tid + 512 * it;
        const int nt = e >> 6, ln = e & 63;
        const int row = nt * 16 + (ln & 15);
        const float4 a = *(const float4*)&W_in[row * 32 + (ln >> 4) * 8];
        const float4 b = *(const float4*)&W_in[row * 32 + (ln >> 4) * 8 + 4];
        *(v8h*)&win_f[nt][ln * 8] = pack8(a, b);
    }
    {   // Wz_out / V / W_out: 8 K-tiles each, 1 entry/thread
        const int kt = tid >> 6, ln = tid & 63;
        const int j0 = (ln >> 4) * 8;
        v8h rz = {};
        if ((ln & 15) < 8) {  // B[k][r] = Wz_out[r][k]
            const float4 a = *(const float4*)&Wz_out[(ln & 15) * 256 + kt * 32 + j0];
            const float4 b = *(const float4*)&Wz_out[(ln & 15) * 256 + kt * 32 + j0 + 4];
            rz = pack8(a, b);
        }
        *(v8h*)&wzout_f[kt][ln * 8] = rz;
        v8h rv = {};
        if ((ln & 15) < 8) {  // B[k][r] = V[k][r]
            #pragma unroll
            for (int j = 0; j < 8; ++j)
                rv[j] = (f16)V[(kt * 32 + j0 + j) * 8 + (ln & 15)];
        }
        *(v8h*)&vv_f[kt][ln * 8] = rv;
        // B[k][y] = W_out[y][k]
        const float4 a = *(const float4*)&W_out[(ln & 15) * 256 + kt * 32 + j0];
        const float4 b = *(const float4*)&W_out[(ln & 15) * 256 + kt * 32 + j0 + 4];
        *(v8h*)&wout_f[kt][ln * 8] = pack8(a, b);
    }
    if (tid < 8)  bzo8[tid] = bz_out[tid];
    if (tid < 16) bo16[tid] = b_out[tid];
    __syncthreads();

    v4f zacc0 = {0,0,0,0}, zacc1 = {0,0,0,0};
    v4f hacc0 = {0,0,0,0}, hacc1 = {0,0,0,0};
    int cur = 0;
    const int prow = tid >> 5, pcol = tid & 31;

    for (int t = 0; t < T_STEPS; ++t) {
        // prefetch next step's inputs (consumed in P4)
        float pfs = 0.f, pfc = 0.f;
        if (t + 1 < T_STEPS) {
            pfs = s[((size_t)(t + 1) * BATCH + bm + prow) * 32 + pcol];
            pfc = c[((size_t)(t + 1) * BATCH + bm + prow) * 32 + pcol];
        }

        // ================= P1 =================
        const v8h ath = lda<512>(thh[cur], lr, lg, w);  // tanh(h_{t-1}) K-slice
        {   // hp partial: th @ V  (K-split, wave w does kt=w)
            const v8h vb = *(const v8h*)&vv_f[w][l * 8];
            v4f z4 = {0,0,0,0};
            v4f ph = __builtin_amdgcn_mfma_f32_16x16x32_f16(ath, vb, z4, 0, 0, 0);
            if (lr < 8) {
                #pragma unroll
                for (int r = 0; r < 4; ++r) php[w][lg * 4 + r][lr] = ph[r];
            }
        }
        if (t > 0) {  // out(t-1) partial: th @ W_out^T (K-split)
            const v8h wb = *(const v8h*)&wout_f[w][l * 8];
            v4f z4 = {0,0,0,0};
            v4f po = __builtin_amdgcn_mfma_f32_16x16x32_f16(ath, wb, z4, 0, 0, 0);
            #pragma unroll
            for (int r = 0; r < 4; ++r) pout[w][lg * 4 + r][lr] = po[r];
        }
        // z-GEMM: C_in = 99*z + bz; += tanh(z)@W_zz^T + [s|c]@Wz_in^T
        v4f a0 = zacc0 * 99.0f + bzv0;
        v4f a1 = zacc1 * 99.0f + bzv1;
        #pragma unroll
        for (int kt = 0; kt < 8; ++kt) {
            const v8h az = lda<512>(tzh[cur], lr, lg, kt);
            a0 = __builtin_amdgcn_mfma_f32_16x16x32_f16(az, wzz0[kt], a0, 0, 0, 0);
            a1 = __builtin_amdgcn_mfma_f32_16x16x32_f16(az, wzz1[kt], a1, 0, 0, 0);
        }
        #pragma unroll
        for (int kt = 0; kt < 2; ++kt) {
            const v8h as = lda<128>(sclh[cur], lr, lg, kt);
            const v8h b0 = *(const v8h*)&wzin_f[(2 * w + 0) * 2 + kt][l * 8];
            const v8h b1 = *(const v8h*)&wzin_f[(2 * w + 1) * 2 + kt][l * 8];
            a0 = __builtin_amdgcn_mfma_f32_16x16x32_f16(as, b0, a0, 0, 0, 0);
            a1 = __builtin_amdgcn_mfma_f32_16x16x32_f16(as, b1, a1, 0, 0, 0);
        }
        zacc0 = a0 * 0.01f;
        zacc1 = a1 * 0.01f;
        {   // store z (f32 states), publish z (f16) and tanh(z) (f16)
            float* st = &states[((size_t)t * BATCH + bm) * 512];
            #pragma unroll
            for (int r = 0; r < 4; ++r) {
                const int m = lg * 4 + r;
                st[(size_t)m * 512 + n0] = zacc0[r];
                st[(size_t)m * 512 + n1] = zacc1[r];
                sta<512>(zfl, m, n0, (f16)zacc0[r]);
                sta<512>(zfl, m, n1, (f16)zacc1[r]);
                sta<512>(tzh[cur ^ 1], m, n0, (f16)fast_tanh(zacc0[r]));
                sta<512>(tzh[cur ^ 1], m, n1, (f16)fast_tanh(zacc1[r]));
            }
        }
        __syncthreads();  // B1

        // ================= P2 =================
        {   // sig partial: z_t @ Wz_out^T (K-split)
            const v8h azf = lda<512>(zfl, lr, lg, w);
            const v8h zb = *(const v8h*)&wzout_f[w][l * 8];
            v4f z4 = {0,0,0,0};
            v4f ps = __builtin_amdgcn_mfma_f32_16x16x32_f16(azf, zb, z4, 0, 0, 0);
            if (lr < 8) {
                #pragma unroll
                for (int r = 0; r < 4; ++r) psig[w][lg * 4 + r][lr] = ps[r];
            }
        }
        if (w < 4 && t > 0) {  // out reduce + store
            const int m = w * 4 + lg;
            float o = bo16[lr];
            #pragma unroll
            for (int ww = 0; ww < 8; ++ww) o += pout[ww][m][lr];
            out[((size_t)(t - 1) * BATCH + bm + m) * 16 + lr] = o;
        }
        if (w == 4) {  // hp reduce
            #pragma unroll
            for (int ee = 0; ee < 2; ++ee) {
                const int e = l + 64 * ee;
                const int m = e >> 3, r = e & 7;
                float hs = 0.f;
                #pragma unroll
                for (int ww = 0; ww < 8; ++ww) hs += php[ww][m][r];
                hpv[m][r] = hs;
            }
        }
        __syncthreads();  // B2

        // ================= P3 ================= (wave 0: sigmoid * hp -> gm)
        if (w == 0) {
            #pragma unroll
            for (int ee = 0; ee < 2; ++ee) {
                const int e = l + 64 * ee;
                const int m = e >> 3, r = e & 7;
                float zs = bzo8[r];
                #pragma unroll
                for (int ww = 0; ww < 8; ++ww) zs += psig[ww][m][r];
                const float sg = 1.0f / (1.0f + __expf(-zs));
                sta<64>(gml, m, r, (f16)(sg * hpv[m][r]));
            }
        }
        __syncthreads();  // B3

        // ================= P4 =================
        v4f h0 = hacc0 * 9.0f + biv0;
        v4f h1 = hacc1 * 9.0f + biv1;
        {
            const v8h ag = lda<64>(gml, lr, lg, 0);
            h0 = __builtin_amdgcn_mfma_f32_16x16x32_f16(ag, u0, h0, 0, 0, 0);
            h1 = __builtin_amdgcn_mfma_f32_16x16x32_f16(ag, u1, h1, 0, 0, 0);
            const v8h as = lda<128>(sclh[cur], lr, lg, 0);  // s part only (k<32)
            const v8h wb0 = *(const v8h*)&win_f[2 * w + 0][l * 8];
            const v8h wb1 = *(const v8h*)&win_f[2 * w + 1][l * 8];
            h0 = __builtin_amdgcn_mfma_f32_16x16x32_f16(as, wb0, h0, 0, 0, 0);
            h1 = __builtin_amdgcn_mfma_f32_16x16x32_f16(as, wb1, h1, 0, 0, 0);
        }
        hacc0 = h0 * 0.1f;
        hacc1 = h1 * 0.1f;
        {
            float* st = &states[((size_t)t * BATCH + bm) * 512 + 256];
            #pragma unroll
            for (int r = 0; r < 4; ++r) {
                const int m = lg * 4 + r;
                st[(size_t)m * 512 + n0] = hacc0[r];
                st[(size_t)m * 512 + n1] = hacc1[r];
                sta<512>(thh[cur ^ 1], m, n0, (f16)fast_tanh(hacc0[r]));
                sta<512>(thh[cur ^ 1], m, n1, (f16)fast_tanh(hacc1[r]));
            }
        }
        if (t + 1 < T_STEPS) {  // publish prefetched inputs for t+1
            sta<128>(sclh[cur ^ 1], prow, pcol, (f16)pfs);
            sta<128>(sclh[cur ^ 1], prow, 32 + pcol, (f16)pfc);
        }
        cur ^= 1;
        __syncthreads();  // B4
    }

    // ---- epilogue: out(T-1) ----
    {
        const v8h ath = lda<512>(thh[cur], lr, lg, w);
        const v8h wb = *(const v8h*)&wout_f[w][l * 8];
        v4f z4 = {0,0,0,0};
        v4f po = __builtin_amdgcn_mfma_f32_16x16x32_f16(ath, wb, z4, 0, 0, 0);
        #pragma unroll
        for (int r = 0; r < 4; ++r) pout[w][lg * 4 + r][lr] = po[r];
    }
    __syncthreads();
    if (w < 4) {
        const int m = w * 4 + lg;
        float o = bo16[lr];
        #pragma unroll
        for (int ww = 0; ww < 8; ++ww) o += pout[ww][m][lr];
        out[((size_t)(T_STEPS - 1) * BATCH + bm + m) * 16 + lr] = o;
    }
}

extern "C" void kernel_launch(void* const* d_in, const int* in_sizes, int n_in,
                              void* d_out, int out_size, void* d_ws, size_t ws_size,
                              hipStream_t stream) {
    const float* s     = (const float*)d_in[0];
    const float* c     = (const float*)d_in[1];
    const float* W_zz  = (const float*)d_in[2];
    const float* Wz_in = (const float*)d_in[3];
    const float* bz_in = (const float*)d_in[4];
    const float* Wz_out= (const float*)d_in[5];
    const float* bz_out= (const float*)d_in[6];
    const float* U     = (const float*)d_in[7];
    const float* V     = (const float*)d_in[8];
    const float* W_in  = (const float*)d_in[9];
    const float* b_in  = (const float*)d_in[10];
    const float* W_out = (const float*)d_in[11];
    const float* b_out = (const float*)d_in[12];

    float* out    = (float*)d_out;
    float* states = out + (size_t)T_STEPS * BATCH * 16;

    hipLaunchKernelGGL(nmrnn_mfma, dim3(BATCH / 16), dim3(512), 0, stream,
                       s, c, W_zz, Wz_in, bz_in, Wz_out, bz_out, U, V,
                       W_in, b_in, W_out, b_out, out, states);
}